// Round 12
// baseline (168.931 us; speedup 1.0000x reference)
//
#include <hip/hip_runtime.h>

#define T_STEPS 512
#define BATCH 64

// fp32 casts of np.exp(-1/20), np.exp(-1/5)
__device__ constexpr float ALPHA_ = 0.95122942450071400910f;
__device__ constexpr float BETA_  = 0.81873075307798185867f;

typedef __attribute__((ext_vector_type(4))) int   i32x4;
typedef __attribute__((ext_vector_type(4))) float f32x4;

// ---------------------------------------------------------------------------
// scale slots: slots[i] = bits of max|W_i| (scaled), via deterministic atomicMax
// ---------------------------------------------------------------------------
__global__ void zero_slots(unsigned int* __restrict__ slots) {
  if (threadIdx.x < 3) slots[threadIdx.x] = 0u;
}

__global__ void prep_maxabs(const float* __restrict__ W, const float* __restrict__ s,
                            unsigned int* __restrict__ slot, int K, int N) {
  const int stride = gridDim.x * 256;
  float m = 0.f;
  for (int i = blockIdx.x * 256 + threadIdx.x; i < K * N; i += stride) {
    float w = W[i];
    if (s) w *= s[i / N];
    m = fmaxf(m, fabsf(w));
  }
#pragma unroll
  for (int o = 32; o > 0; o >>= 1) m = fmaxf(m, __shfl_xor(m, o));
  if ((threadIdx.x & 63) == 0) atomicMax(slot, __float_as_uint(m));
}

// ---------------------------------------------------------------------------
// Two-level i8 quantization of W (optionally LN-scale s[k] pre-multiplied),
// written in the fragment-linear global layout the GEMM's B loads expect:
// unit g = ((cb*KB + kb)*256 + n16*64 + lane); bytes jj=0..15 hold
// col = cb*64 + n16*16 + (lane&15), k = kb*64 + (lane>>4)*16 + jj.
// w ~= s1*h1 + s2*h2, s1 = max/127, s2 = s1/254 -> |err| <= s1/508.
// ---------------------------------------------------------------------------
__global__ void prep_quant(const float* __restrict__ W, const float* __restrict__ s,
                           const unsigned int* __restrict__ slot,
                           char* __restrict__ H1, char* __restrict__ H2,
                           int K, int N) {
  const int g = blockIdx.x * 256 + threadIdx.x;
  const int total = (K * N) / 16;
  if (g >= total) return;
  const float maxv = fmaxf(__uint_as_float(*slot), 1e-30f);
  const float s1 = maxv * (1.0f / 127.0f);
  const float s2 = s1 * (1.0f / 254.0f);
  const float inv1 = 1.0f / s1, inv2 = 1.0f / s2;
  const int KB = K / 64;
  const int u = g & 255;
  const int kb = (g >> 8) % KB;
  const int cb = g / (256 * KB);
  const int lane = u & 63;
  const int n = cb * 64 + ((u >> 6) << 4) + (lane & 15);
  const int kbase = kb * 64 + ((lane >> 4) << 4);
  unsigned int w1[4] = {0, 0, 0, 0}, w2[4] = {0, 0, 0, 0};
#pragma unroll
  for (int jj = 0; jj < 16; ++jj) {
    const int k = kbase + jj;
    float w = W[(size_t)k * N + n];
    if (s) w *= s[k];
    const int q1 = (int)rintf(w * inv1);
    const float r = w - (float)q1 * s1;
    const int q2 = (int)rintf(r * inv2);
    w1[jj >> 2] |= ((unsigned int)(q1 & 0xFF)) << ((jj & 3) * 8);
    w2[jj >> 2] |= ((unsigned int)(q2 & 0xFF)) << ((jj & 3) * 8);
  }
  i32x4 v1, v2;
#pragma unroll
  for (int q = 0; q < 4; ++q) { v1[q] = (int)w1[q]; v2[q] = (int)w2[q]; }
  *(i32x4*)(H1 + (size_t)g * 16) = v1;
  *(i32x4*)(H2 + (size_t)g * 16) = v2;
}

// ---------------------------------------------------------------------------
// i8 MFMA GEMM (16x16x64, two-level weights), BM=64 fixed, 4 waves (WM x WC).
//   A: reg-staged -> i8 frag-linear LDS, TRIPLE-buffered (4 KB/buf), ONE
//      barrier/step, depth-2 on the global loads — all compiler-visible
//      (no inline asm, no counted waitcnt).
//   A_F32: fp32 spikes 0.0/1.0 -> i8 via (bits>>29)&1 (exact).
//   B: frag-linear i8 (prep_quant) loaded to regs per wave, L2-resident.
//   Per wave-step: FM*4*2 (+FM ones) MFMA @ K=64, FM ds_read_b128 for A.
//   LNFOLD: rowsum via ones-i8 MFMA (exact); epilogue inv*dot - mi*u + c.
// ---------------------------------------------------------------------------
template <int WM, int WC, int TM, bool A_F32, bool LNFOLD>
__global__ __launch_bounds__(256) void gemm_i8(
    const void* __restrict__ Av, const char* __restrict__ H1,
    const char* __restrict__ H2, const unsigned int* __restrict__ slot,
    const float* __restrict__ uvec, const float* __restrict__ cvec,
    float* __restrict__ C, int N, int K) {
  constexpr int FM = TM / 16;      // m-frags per wave; BM = WM*TM = 64
  __shared__ char smem[3 * 4096];  // triple-buffered 64x64 i8 A tile

  const int tid = threadIdx.x;
  const int lane = tid & 63;
  const int wave = tid >> 6;
  const int wm = wave / WC, wc = wave % WC;
  const int l15 = lane & 15, l4 = lane >> 4;
  const int row0 = blockIdx.y * 64;
  const int KB = K / 64;

  // A staging source: thread owns one 16-elem unit per step
  const int srow = ((tid >> 6) << 4) | (tid & 15);
  const int skoff = ((tid >> 4) & 3) * 16;
  const float* af32 = (const float*)Av + (size_t)(row0 + srow) * K + skoff;
  const char*  ai8  = (const char*)Av + (size_t)(row0 + srow) * K + skoff;

  const size_t bbase = ((size_t)(blockIdx.x * WC + wc) * KB) * 4096 + (size_t)lane * 16;

  i32x4 acc1[FM][4] = {};
  i32x4 acc2[FM][4] = {};
  i32x4 accR[FM] = {};
  const i32x4 ONESB = {0x01010101, 0x01010101, 0x01010101, 0x01010101};

  i32x4 bf1[4], bf2[4];
  f32x4 ar0, ar1, ar2, ar3;  // fp32 staging regs (A_F32)
  i32x4 apack;               // i8 staging reg (A_I8)

  auto loadA = [&](int kb) {
    if constexpr (A_F32) {
      const float* p = af32 + (size_t)kb * 64;
      ar0 = *(const f32x4*)(p);
      ar1 = *(const f32x4*)(p + 4);
      ar2 = *(const f32x4*)(p + 8);
      ar3 = *(const f32x4*)(p + 12);
    } else {
      apack = *(const i32x4*)(ai8 + (size_t)kb * 64);
    }
  };
  auto packA = [&]() -> i32x4 {
    if constexpr (A_F32) {
      i32x4 r;
      const f32x4 vv[4] = {ar0, ar1, ar2, ar3};
#pragma unroll
      for (int q = 0; q < 4; ++q) {
        const f32x4 v = vv[q];
        r[q] = (int)(((__float_as_uint(v.x) >> 29) & 1u) |
                     (((__float_as_uint(v.y) >> 29) & 1u) << 8) |
                     (((__float_as_uint(v.z) >> 29) & 1u) << 16) |
                     (((__float_as_uint(v.w) >> 29) & 1u) << 24));
      }
      return r;
    } else {
      return apack;
    }
  };
  auto loadB = [&](int kb) {
    const char* p1 = H1 + bbase + (size_t)kb * 4096;
    const char* p2 = H2 + bbase + (size_t)kb * 4096;
#pragma unroll
    for (int n = 0; n < 4; ++n) {
      bf1[n] = *(const i32x4*)(p1 + n * 1024);
      bf2[n] = *(const i32x4*)(p2 + n * 1024);
    }
  };

  // ---- prologue: A(0) -> buf0; A(1) -> regs; B(0) -> regs ----
  loadA(0);
  *(i32x4*)(smem + tid * 16) = packA();
  loadA(1);
  loadB(0);
  __syncthreads();

  for (int kb = 0; kb < KB; ++kb) {
    char* bufc = smem + (kb % 3) * 4096;
    char* bufn = smem + ((kb + 1) % 3) * 4096;
    if (kb + 1 < KB) {
      *(i32x4*)(bufn + tid * 16) = packA();              // A(kb+1) regs -> LDS
      loadA(kb + 2 < KB ? kb + 2 : KB - 1);              // issue A(kb+2)
    }
    __syncthreads();  // A(kb) visible (written+barriered last iter)

    i32x4 af[FM];
#pragma unroll
    for (int m = 0; m < FM; ++m)
      af[m] = *(const i32x4*)(bufc + ((wm * FM + m) * 64 + lane) * 16);

#pragma unroll
    for (int m = 0; m < FM; ++m) {
#pragma unroll
      for (int n = 0; n < 4; ++n) {
        acc1[m][n] = __builtin_amdgcn_mfma_i32_16x16x64_i8(af[m], bf1[n], acc1[m][n], 0, 0, 0);
        acc2[m][n] = __builtin_amdgcn_mfma_i32_16x16x64_i8(af[m], bf2[n], acc2[m][n], 0, 0, 0);
      }
      if constexpr (LNFOLD)
        accR[m] = __builtin_amdgcn_mfma_i32_16x16x64_i8(af[m], ONESB, accR[m], 0, 0, 0);
    }
    if (kb + 1 < KB) loadB(kb + 1);  // B(kb+1) after B(kb) consumed
  }

  // ---- epilogue ----
  const float maxv = fmaxf(__uint_as_float(*slot), 1e-30f);
  const float s1 = maxv * (1.0f / 127.0f);
  const float s2 = s1 * (1.0f / 254.0f);
  const int row0w = row0 + wm * TM;
  const int col0w = blockIdx.x * (WC * 64) + wc * 64;
#pragma unroll
  for (int m = 0; m < FM; ++m) {
    const int rbase = row0w + m * 16 + l4 * 4;
    float iv[4], mv[4];
    if constexpr (LNFOLD) {
#pragma unroll
      for (int r = 0; r < 4; ++r) {
        const float mean = (float)accR[m][r] / (float)K;
        const float inv = 1.0f / sqrtf(mean * (1.f - mean) + 1e-6f);
        iv[r] = inv;
        mv[r] = mean * inv;
      }
    }
#pragma unroll
    for (int n = 0; n < 4; ++n) {
      const int c = col0w + n * 16 + l15;
      const float cc = cvec[c];
      float uu = 0.f;
      if constexpr (LNFOLD) uu = uvec[c];
#pragma unroll
      for (int r = 0; r < 4; ++r) {
        const float dot = s1 * (float)acc1[m][n][r] + s2 * (float)acc2[m][n][r];
        float v;
        if constexpr (LNFOLD) v = iv[r] * dot - mv[r] * uu + cc;
        else v = dot + cc;
        C[(size_t)(rbase + r) * N + c] = v;
      }
    }
  }
}

// u[n] = sum_k s[k]*W[k,n];  c[n] = sum_k b[k]*W[k,n] + bias2[n]. Block per n.
__global__ __launch_bounds__(256) void prep_consts(
    const float* __restrict__ W, const float* __restrict__ s,
    const float* __restrict__ b, const float* __restrict__ bias2,
    float* __restrict__ u, float* __restrict__ c, int K, int N) {
  const int n = blockIdx.x;
  const int t = threadIdx.x;
  float us = 0.f, cs = 0.f;
  for (int k = t; k < K; k += 256) {
    const float w = W[(size_t)k * N + n];
    us += s[k] * w;
    cs += b[k] * w;
  }
  __shared__ float su[256], sc[256];
  su[t] = us;
  sc[t] = cs;
  __syncthreads();
  for (int o = 128; o > 0; o >>= 1) {
    if (t < o) { su[t] += su[t + o]; sc[t] += sc[t + o]; }
    __syncthreads();
  }
  if (t == 0) { u[n] = su[0]; c[n] = sc[0] + bias2[n]; }
}

// ---------------------------------------------------------------------------
// LIF scan over T, one thread per (b,h); reads fp32 currents, writes i8
// spikes (0/1) and/or per-(b,h) spike counts. 32x unrolled loads.
// ---------------------------------------------------------------------------
template <int H, bool SPIKE_OUT, bool ACCUM>
__global__ void lif_scan(const float* __restrict__ xt,
                         char* __restrict__ sp,
                         float* __restrict__ tsum) {
  const int n = blockIdx.x * 64 + threadIdx.x;
  const int b = n / H, h = n % H;
  const float* p = xt + (size_t)b * T_STEPS * H + h;
  char* q = nullptr;
  if constexpr (SPIKE_OUT) q = sp + (size_t)b * T_STEPS * H + h;

  float v = 0.f, cur = 0.f, ts = 0.f;
  for (int t = 0; t < T_STEPS; t += 32) {
    float x[32];
#pragma unroll
    for (int u = 0; u < 32; ++u) x[u] = p[(size_t)u * H];
#pragma unroll
    for (int u = 0; u < 32; ++u) {
      cur = BETA_ * cur + x[u];
      v = ALPHA_ * v + cur;
      const bool sb = (v >= 1.f);
      if constexpr (SPIKE_OUT) q[(size_t)u * H] = sb ? (char)1 : (char)0;
      if constexpr (ACCUM) ts += sb ? 1.f : 0.f;
      v = sb ? 0.f : v;
    }
    p += (size_t)32 * H;
    if constexpr (SPIKE_OUT) q += (size_t)32 * H;
  }
  if constexpr (ACCUM) tsum[n] = ts;
}

__global__ void finalize(const float* __restrict__ tsum,
                         const float* __restrict__ Wc,
                         const float* __restrict__ bc,
                         float* __restrict__ out) {
  const int b = threadIdx.x;  // 64 threads, one wave
  float s = 0.f;
#pragma unroll 8
  for (int h = 0; h < 64; ++h) s += tsum[b * 64 + h];
  const float pooled = s * (1.0f / (512.f * 64.f));
  out[2 + b] = pooled;

  float tot = pooled;
  float l0 = pooled * Wc[b * 2 + 0];
  float l1 = pooled * Wc[b * 2 + 1];
#pragma unroll
  for (int off = 32; off > 0; off >>= 1) {
    tot += __shfl_xor(tot, off);
    l0 += __shfl_xor(l0, off);
    l1 += __shfl_xor(l1, off);
  }
  if (b == 0) {
    out[0] = l0 + bc[0];
    out[1] = l1 + bc[1];
    out[66] = tot * (1.0f / 64.f);
  }
}

extern "C" void kernel_launch(void* const* d_in, const int* in_sizes, int n_in,
                              void* d_out, int out_size, void* d_ws, size_t ws_size,
                              hipStream_t stream) {
  const float* X    = (const float*)d_in[0];   // [64,512,64,16] -> [32768,1024]
  const float* W0   = (const float*)d_in[1];   // [1024,256]
  const float* b0   = (const float*)d_in[2];
  const float* W1   = (const float*)d_in[3];   // [256,128]
  const float* b1   = (const float*)d_in[4];
  const float* W2   = (const float*)d_in[5];   // [128,64]
  const float* b2   = (const float*)d_in[6];
  const float* ln1s = (const float*)d_in[7];
  const float* ln1b = (const float*)d_in[8];
  const float* ln2s = (const float*)d_in[9];
  const float* ln2b = (const float*)d_in[10];
  const float* Wc   = (const float*)d_in[11];  // [64,2]
  const float* bc   = (const float*)d_in[12];
  float* out = (float*)d_out;

  char* w = (char*)d_ws;
  float* buf0 = (float*)w;                   // [32768,256] f32 = 33554432 B
  float* buf1 = (float*)w;                   // alias: buf0 dead after scan0
  float* buf2 = (float*)(w + 16777216);      // [32768,64] f32
  size_t off = 33554432;
  char* sp0 = w + off; off += 8388608;       // [32768,256] i8
  char* sp1 = w + off; off += 4194304;       // [32768,128] i8
  char* h1_0 = w + off; off += 262144;
  char* h2_0 = w + off; off += 262144;
  char* h1_1 = w + off; off += 32768;
  char* h2_1 = w + off; off += 32768;
  char* h1_2 = w + off; off += 8192;
  char* h2_2 = w + off; off += 8192;
  float* u1 = (float*)(w + off); off += 512;
  float* c1 = (float*)(w + off); off += 512;
  float* u2 = (float*)(w + off); off += 256;
  float* c2 = (float*)(w + off); off += 256;
  unsigned int* slots = (unsigned int*)(w + off); off += 256;
  float* tsum = (float*)(w + off); off += 16384;

  const int M = 32768;

  // --- scales (deterministic atomicMax) + two-level i8 weight prep ---
  zero_slots<<<1, 64, 0, stream>>>(slots);
  prep_maxabs<<<64, 256, 0, stream>>>(W0, nullptr, slots + 0, 1024, 256);
  prep_maxabs<<<16, 256, 0, stream>>>(W1, ln1s, slots + 1, 256, 128);
  prep_maxabs<<<8, 256, 0, stream>>>(W2, ln2s, slots + 2, 128, 64);
  prep_quant<<<(1024 * 256 / 16 + 255) / 256, 256, 0, stream>>>(
      W0, nullptr, slots + 0, h1_0, h2_0, 1024, 256);
  prep_quant<<<(256 * 128 / 16 + 255) / 256, 256, 0, stream>>>(
      W1, ln1s, slots + 1, h1_1, h2_1, 256, 128);
  prep_quant<<<(128 * 64 / 16 + 255) / 256, 256, 0, stream>>>(
      W2, ln2s, slots + 2, h1_2, h2_2, 128, 64);
  prep_consts<<<128, 256, 0, stream>>>(W1, ln1s, ln1b, b1, u1, c1, 256, 128);
  prep_consts<<<64, 256, 0, stream>>>(W2, ln2s, ln2b, b2, u2, c2, 128, 64);

  // --- layer 0: xt = X @ W0 + b0. i8 MFMA K=64, BM=64, BN=128 (2x2 waves),
  //     grid (2,512) = 1024 blocks. A fp32->i8 in-register (exact). ---
  gemm_i8<2, 2, 32, true, false><<<dim3(2, M / 64), 256, 0, stream>>>(
      X, h1_0, h2_0, slots + 0, nullptr, b0, buf0, 256, 1024);
  lif_scan<256, true, false><<<(BATCH * 256) / 64, 64, 0, stream>>>(buf0, sp0, nullptr);

  // --- layer 1: LN folded (rowsum via ones-MFMA). BM=64, BN=64, grid (2,512).
  gemm_i8<4, 1, 16, false, true><<<dim3(2, M / 64), 256, 0, stream>>>(
      sp0, h1_1, h2_1, slots + 1, u1, c1, buf1, 128, 256);
  lif_scan<128, true, false><<<(BATCH * 128) / 64, 64, 0, stream>>>(buf1, sp1, nullptr);

  // --- layer 2: BM=64, BN=64, grid (1,512). ---
  gemm_i8<4, 1, 16, false, true><<<dim3(1, M / 64), 256, 0, stream>>>(
      sp1, h1_2, h2_2, slots + 2, u2, c2, buf2, 64, 128);
  lif_scan<64, false, true><<<(BATCH * 64) / 64, 64, 0, stream>>>(buf2, nullptr, tsum);

  finalize<<<1, 64, 0, stream>>>(tsum, Wc, bc, out);
}